// Round 3
// baseline (64.747 us; speedup 1.0000x reference)
//
#include <hip/hip_runtime.h>

#define NROW 4096      // 64*64 patch positions
#define NCOL 4225      // 65*65 plane
#define BATCH 8
#define MAGIC_HI 0x13579BDFu

// ws layout: unsigned long long slot[256];  -- {MAGIC_HI, float_bits} per block

// fast tanh for |x| <~ 4: tanh(x) = 1 - 2/(e^{2x}+1), e^{2x} via exp2
__device__ __forceinline__ float fast_tanh(float x) {
    float e = __builtin_exp2f(2.885390082f * x);   // 2*log2(e)*x
    return 1.0f - 2.0f / (e + 1.0f);
}

// Single dispatch: 256 blocks x 1024 threads (1 block/CU, 4 waves/SIMD).
// Cross-block completion protocol is ONE 64-bit atomicExch per block:
// high word = MAGIC_HI (completion flag), low word = float bits of the partial.
// Flag and value travel in the same atomic word -> no __threadfence anywhere
// (R0's 256 fences each forced an L2 writeback against 268 MB of dirty
// poison-fill lines -- that was the protocol's real cost).
__global__ void __launch_bounds__(1024) k_fused(const float* __restrict__ x,
                                                const float* __restrict__ proj_w,
                                                const float* __restrict__ proj_b,
                                                float* __restrict__ out,
                                                unsigned long long* __restrict__ slot) {
    __shared__ __align__(16) float cs_sh[NCOL];   // batch-summed plane
    __shared__ __align__(16) float s_sh[NROW];    // tanh scalars
    __shared__ float c_sh[16];                    // per-row softmax results
    const int tid = threadIdx.x;
    const int bid = blockIdx.x;

    // phase 1: colsum[p] = sum_b x[b,p]; 4 positions/thread + 129 tail
#pragma unroll
    for (int k = 0; k < 4; ++k) {
        int p = tid + (k << 10);
        float v = 0.0f;
#pragma unroll
        for (int b = 0; b < BATCH; ++b) v += x[b * NCOL + p];
        cs_sh[p] = v;
    }
    if (tid < NCOL - NROW) {       // 129-element tail
        int p = NROW + tid;
        float v = 0.0f;
#pragma unroll
        for (int b = 0; b < BATCH; ++b) v += x[b * NCOL + p];
        cs_sh[p] = v;
    }
    __syncthreads();

    // phase 2: s[n] = tanh(2x2 patch sum / 32) — 4 per thread, branch-free tanh
#pragma unroll
    for (int k = 0; k < 4; ++k) {
        int n = tid + (k << 10);
        int i = n >> 6, j = n & 63;
        const float* c = &cs_sh[i * 65 + j];
        s_sh[n] = fast_tanh((c[0] + c[1] + c[65] + c[66]) * (1.0f / 32.0f));
    }
    __syncthreads();

    // phase 3: wave w -> row bid*16+w. 64 lanes sweep all 4096 m via float4 LDS
    // reads (ds_read_b128, conflict-free: 64 lanes x 16B consecutive).
    const int wave = tid >> 6;
    const int lane = tid & 63;
    const int row = (bid << 4) + wave;
    const float t = 8.0f * 1.4426950408889634f * s_sh[row];  // fold log2(e)
    float num = 0.0f, den = 0.0f;
    const float4* s4 = (const float4*)s_sh;
#pragma unroll
    for (int k = 0; k < 16; ++k) {
        float4 sv = s4[lane + (k << 6)];
        float e0 = __builtin_exp2f(t * sv.x);  // |arg| < 11.6, no max-subtract
        float e1 = __builtin_exp2f(t * sv.y);
        float e2 = __builtin_exp2f(t * sv.z);
        float e3 = __builtin_exp2f(t * sv.w);
        num += e0 * sv.x;
        den += e0;
        num += e1 * sv.y;
        den += e1;
        num += e2 * sv.z;
        den += e2;
        num += e3 * sv.w;
        den += e3;
    }
#pragma unroll
    for (int off = 32; off; off >>= 1) {
        num += __shfl_down(num, off, 64);
        den += __shfl_down(den, off, 64);
    }
    if (lane == 0) c_sh[wave] = num / den;
    __syncthreads();

    // phase 4: publish {flag, value} in one fence-free 64-bit atomic
    if (tid == 0) {
        float bs = 0.0f;
#pragma unroll
        for (int r = 0; r < 16; ++r) bs += c_sh[r];
        unsigned long long pk = ((unsigned long long)MAGIC_HI << 32)
                              | (unsigned long long)__float_as_uint(bs);
        atomicExch(&slot[bid], pk);
    }

    // phase 5: block 0, wave 0 finalizes. Spin reads the 64-bit word; the flag
    // arriving implies the value is in the same word -> no ordering needed.
    // All other blocks retire unconditionally -> no deadlock under any scheduling.
    if (bid == 0 && tid < 64) {
        float pw = proj_w[tid];    // hoist: overlap load latency with the spin
        float pb = proj_b[0];
        float acc = 0.0f;
#pragma unroll
        for (int q = 0; q < 4; ++q) {
            int i = tid + (q << 6);
            unsigned long long v;
            while (((unsigned)((v = atomicAdd(&slot[i], 0ull)) >> 32)) != MAGIC_HI)
                __builtin_amdgcn_s_sleep(1);
            acc += __uint_as_float((unsigned)v);   // same q-order as k_final -> bit-identical
        }
#pragma unroll
        for (int off = 32; off; off >>= 1) {
            acc += __shfl_down(acc, off, 64);
            pw  += __shfl_down(pw, off, 64);
        }
        if (tid == 0) {
            float o = (acc * (1.0f / (float)NROW)) * pw + pb;
#pragma unroll
            for (int b = 0; b < BATCH; ++b) out[b] = o;
        }
    }
}

extern "C" void kernel_launch(void* const* d_in, const int* in_sizes, int n_in,
                              void* d_out, int out_size, void* d_ws, size_t ws_size,
                              hipStream_t stream) {
    const float* x      = (const float*)d_in[0];
    const float* proj_w = (const float*)d_in[1];
    const float* proj_b = (const float*)d_in[2];
    float* out = (float*)d_out;

    unsigned long long* slot = (unsigned long long*)d_ws;

    k_fused<<<256, 1024, 0, stream>>>(x, proj_w, proj_b, out, slot);
}